// Round 7
// baseline (365.542 us; speedup 1.0000x reference)
//
#include <hip/hip_runtime.h>
#include <math.h>

#define NN 8192
#define MM 4096
#define DD 128
#define TDIM 32
#define H1DIM 64
#define H2DIM 32
#define FEAT (3*DD + TDIM)   // 416
#define KGROUPS (FEAT/4)     // 104
#define MAXK 256
#define BIGF 1e30f
#define PACK_N (FEAT*H1DIM + H1DIM*H2DIM)   // 28672

typedef float fvec4 __attribute__((ext_vector_type(4)));

// ===== MEASUREMENT ROUND =====
// Pipeline identical to R6; stats_mlp is launched 1 + 16 times (idempotent:
// same out values rewritten). Marginal cost of the 16 extra launches measures
// (warm stats_mlp + per-node graph overhead) to decide csc-attack vs fusion.

__global__ void csc_pack(const float* __restrict__ H,
                         const float* __restrict__ W1, const float* __restrict__ W2,
                         int* __restrict__ cnt, int* __restrict__ idxlist,
                         float* __restrict__ W1P, float* __restrict__ W2T) {
    const int tid = threadIdx.x;
    if (blockIdx.x == 0) {
        for (int i = tid; i < PACK_N; i += 256) {
            if (i < FEAT * H1DIM) {
                int c = i & 3, j = (i >> 2) & 63, g = i >> 8;
                W1P[i] = W1[j * FEAT + g * 4 + c];      // W1P4[g*64+j] = W1[j][4g..]
            } else {
                int t2 = i - FEAT * H1DIM;
                W2T[t2] = W2[(t2 & 31) * H1DIM + (t2 >> 5)];
            }
        }
    }
    const fvec4* H4 = reinterpret_cast<const fvec4*>(H);
    int t0 = blockIdx.x * 1024 + tid;
    #pragma unroll
    for (int k = 0; k < 4; ++k) {
        int idx4 = t0 + k * 256;
        fvec4 v = H4[idx4];
        if (v.x != 0.f || v.y != 0.f || v.z != 0.f || v.w != 0.f) {
            int base = idx4 * 4;
            int n    = base >> 12;              // node (row), MM=4096
            int mcol = base & (MM - 1);         // hyperedge (col)
            float vals[4] = {v.x, v.y, v.z, v.w};
            #pragma unroll
            for (int c = 0; c < 4; ++c) {
                if (vals[c] != 0.0f) {
                    int p = atomicAdd(&cnt[mcol + c], 1);
                    if (p < MAXK) idxlist[(mcol + c) * MAXK + p] = n;
                }
            }
        }
    }
}

__global__ __launch_bounds__(256) void stats_mlp(
        const float* __restrict__ x,
        const int* __restrict__ cnt, const int* __restrict__ idxlist,
        const float* __restrict__ tptr, const float* __restrict__ Wt,
        const float* __restrict__ bt,
        const float* __restrict__ W1P, const float* __restrict__ b1,
        const float* __restrict__ W2T, const float* __restrict__ b2,
        const float* __restrict__ W3, const float* __restrict__ b3,
        float* __restrict__ out) {
    const int tid = threadIdx.x;
    const int wave = tid >> 6, lane = tid & 63;
    const int m = blockIdx.x * 4 + wave;

    __shared__ float lsf[4][FEAT];
    __shared__ float hs1[4][H1DIM];

    {
        int K = cnt[m]; if (K > MAXK) K = MAXK;
        const int* lst = idxlist + m * MAXK;
        float sx = 0.f, sy = 0.f, s2x = 0.f, s2y = 0.f;
        float mxx = -BIGF, mxy = -BIGF, mnx = BIGF, mny = BIGF;
        const float* xb = x + 2 * lane;
        int i = 0;
        for (; i + 4 <= K; i += 4) {
            int4 nv = *reinterpret_cast<const int4*>(lst + i);
            float2 v0 = *reinterpret_cast<const float2*>(xb + nv.x * DD);
            float2 v1 = *reinterpret_cast<const float2*>(xb + nv.y * DD);
            float2 v2 = *reinterpret_cast<const float2*>(xb + nv.z * DD);
            float2 v3 = *reinterpret_cast<const float2*>(xb + nv.w * DD);
            sx  += (v0.x + v1.x) + (v2.x + v3.x);
            sy  += (v0.y + v1.y) + (v2.y + v3.y);
            s2x += (v0.x*v0.x + v1.x*v1.x) + (v2.x*v2.x + v3.x*v3.x);
            s2y += (v0.y*v0.y + v1.y*v1.y) + (v2.y*v2.y + v3.y*v3.y);
            mxx = fmaxf(mxx, fmaxf(fmaxf(v0.x, v1.x), fmaxf(v2.x, v3.x)));
            mxy = fmaxf(mxy, fmaxf(fmaxf(v0.y, v1.y), fmaxf(v2.y, v3.y)));
            mnx = fminf(mnx, fminf(fminf(v0.x, v1.x), fminf(v2.x, v3.x)));
            mny = fminf(mny, fminf(fminf(v0.y, v1.y), fminf(v2.y, v3.y)));
        }
        for (; i < K; ++i) {
            float2 v = *reinterpret_cast<const float2*>(xb + lst[i] * DD);
            sx += v.x; sy += v.y; s2x += v.x*v.x; s2y += v.y*v.y;
            mxx = fmaxf(mxx, v.x); mxy = fmaxf(mxy, v.y);
            mnx = fminf(mnx, v.x); mny = fminf(mny, v.y);
        }
        float deg = (K > 0) ? (float)K : 1.0f;
        float mux = sx / deg, muy = sy / deg;
        float sgx = sqrtf(fmaxf(s2x / deg - mux * mux, 1e-8f));
        float sgy = sqrtf(fmaxf(s2y / deg - muy * muy, 1e-8f));
        float dlx = (K > 0) ? (mxx - mnx) : 0.0f;
        float dly = (K > 0) ? (mxy - mny) : 0.0f;
        float* f = lsf[wave];
        f[2*lane]            = mux;  f[2*lane + 1]          = muy;
        f[DD + 2*lane]       = sgx;  f[DD + 2*lane + 1]     = sgy;
        f[2*DD + 2*lane]     = dlx;  f[2*DD + 2*lane + 1]   = dly;
        if (lane < TDIM)
            f[3*DD + lane] = fmaxf(tptr[0] * Wt[lane] + bt[lane], 0.0f);
    }
    __syncthreads();

    if (wave == 0) {
        const float4* W1P4 = reinterpret_cast<const float4*>(W1P);
        const float4* f0 = reinterpret_cast<const float4*>(lsf[0]);
        const float4* f1 = reinterpret_cast<const float4*>(lsf[1]);
        const float4* f2 = reinterpret_cast<const float4*>(lsf[2]);
        const float4* f3 = reinterpret_cast<const float4*>(lsf[3]);

        float bb = b1[lane];
        float acc0 = bb, acc1 = bb, acc2 = bb, acc3 = bb;
        #pragma unroll 4
        for (int g = 0; g < KGROUPS; ++g) {
            float4 w = W1P4[g * H1DIM + lane];
            float4 a0 = f0[g];
            float4 a1 = f1[g];
            float4 a2 = f2[g];
            float4 a3 = f3[g];
            acc0 += a0.x*w.x + a0.y*w.y + a0.z*w.z + a0.w*w.w;
            acc1 += a1.x*w.x + a1.y*w.y + a1.z*w.z + a1.w*w.w;
            acc2 += a2.x*w.x + a2.y*w.y + a2.z*w.z + a2.w*w.w;
            acc3 += a3.x*w.x + a3.y*w.y + a3.z*w.z + a3.w*w.w;
        }
        hs1[0][lane] = fmaxf(acc0, 0.f);
        hs1[1][lane] = fmaxf(acc1, 0.f);
        hs1[2][lane] = fmaxf(acc2, 0.f);
        hs1[3][lane] = fmaxf(acc3, 0.f);

        int j2 = lane & 31;
        int kh = (lane >> 5) * 32;
        float w3v = W3[j2];
        float b2v = b2[j2];
        #pragma unroll
        for (int r = 0; r < 4; ++r) {
            float a2 = 0.f;
            #pragma unroll
            for (int kk = 0; kk < 32; ++kk) {
                int k = kh + kk;
                a2 += hs1[r][k] * W2T[k * H2DIM + j2];
            }
            a2 += __shfl_xor(a2, 32);
            float h2 = fmaxf(a2 + b2v, 0.f);
            float p = h2 * w3v;
            p += __shfl_xor(p, 16);
            p += __shfl_xor(p, 8);
            p += __shfl_xor(p, 4);
            p += __shfl_xor(p, 2);
            p += __shfl_xor(p, 1);
            if (lane == 0) out[blockIdx.x * 4 + r] = 1.f / (1.f + expf(-(p + b3[0])));
        }
    }
}

extern "C" void kernel_launch(void* const* d_in, const int* in_sizes, int n_in,
                              void* d_out, int out_size, void* d_ws, size_t ws_size,
                              hipStream_t stream) {
    const float* x   = (const float*)d_in[0];
    const float* H   = (const float*)d_in[1];
    const float* t   = (const float*)d_in[2];
    const float* Wt  = (const float*)d_in[3];
    const float* bt  = (const float*)d_in[4];
    const float* W1  = (const float*)d_in[5];
    const float* b1  = (const float*)d_in[6];
    const float* W2  = (const float*)d_in[7];
    const float* b2  = (const float*)d_in[8];
    const float* W3  = (const float*)d_in[9];
    const float* b3  = (const float*)d_in[10];
    float* out = (float*)d_out;

    int* cnt     = (int*)d_ws;
    int* idxlist = cnt + MM;
    float* W1P   = (float*)(idxlist + (size_t)MM * MAXK);
    float* W2T   = W1P + FEAT * H1DIM;

    hipMemsetAsync(cnt, 0, MM * sizeof(int), stream);
    csc_pack<<<NN * MM / 4 / 1024, 256, 0, stream>>>(H, W1, W2, cnt, idxlist, W1P, W2T);
    // 1 + 16 identical launches: extras are idempotent; their marginal cost
    // = 16 x (warm stats_mlp + per-node overhead). Measurement only.
    for (int rep = 0; rep < 17; ++rep) {
        stats_mlp<<<MM / 4, 256, 0, stream>>>(x, cnt, idxlist, t, Wt, bt,
                                              W1P, b1, W2T, b2, W3, b3, out);
    }
}

// Round 8
// 69.893 us; speedup vs baseline: 5.2300x; 5.2300x over previous
//
#include <hip/hip_runtime.h>
#include <math.h>

#define NN 8192
#define MM 4096
#define DD 128
#define TDIM 32
#define H1DIM 64
#define H2DIM 32
#define FEAT (3*DD + TDIM)   // 416
#define KGROUPS (FEAT/4)     // 104
#define MAXK 256
#define BIGF 1e30f
#define COLS 16              // hyperedges per block
#define NBLK (MM/COLS)       // 256 blocks
#define NTHR 512             // 8 waves

// LDS layout (bytes):
//   W1P  : 26624 f  = 106496   packed W1: w1p[(g*64+j)*4+c] = W1[j][4g+c]
//   W2T  :  2048 f  =   8192   w2t[k*32+j2] = W2[j2][k]
//   lsf  : 16*416 f =  26624   feature rows
//   hs1  : 16*64 f  =   4096   layer-1 activations
//   lists: 16*256 u16 = 8192   member node indices per edge
//   lcnt : 16 i     =     64   member counts
#define LDS_W1P   0
#define LDS_W2T   106496
#define LDS_LSF   114688
#define LDS_HS1   141312
#define LDS_LISTS 145408
#define LDS_LCNT  153600
#define LDS_TOTAL 153664

typedef float fvec4 __attribute__((ext_vector_type(4)));

// ONE kernel node, no global workspace, no memset, no grid.sync.
// Block b owns hyperedges [16b, 16b+16). Phases (block-local syncs only):
//   P0 prologue: pack W1->LDS (lane-coalesced float4 groups), W2T->LDS, lcnt=0
//   P1 scan:     read the 8192x16 column panel of H (each element once,
//                dwordx4, 4 loads in flight/lane); append nonzero row ids
//                to LDS lists via DS atomics
//   P2 stats:    wave w computes edges 2w,2w+1: mean/sigma/range via
//                coalesced float2 gathers of x rows; feature row -> LDS
//   P3 mlp:      waves 0-3, 4 rows each: 416->64->32->1 sigmoid (R6 shape)
__global__ __launch_bounds__(NTHR, 1) void hyperedge_fused(
        const float* __restrict__ x,   const float* __restrict__ H,
        const float* __restrict__ tptr,const float* __restrict__ Wt,
        const float* __restrict__ bt,
        const float* __restrict__ W1,  const float* __restrict__ b1,
        const float* __restrict__ W2,  const float* __restrict__ b2,
        const float* __restrict__ W3,  const float* __restrict__ b3,
        float* __restrict__ out) {
    extern __shared__ char smem[];
    float*          w1p   = (float*)(smem + LDS_W1P);
    float*          w2t   = (float*)(smem + LDS_W2T);
    float*          lsf   = (float*)(smem + LDS_LSF);    // [16][416]
    float*          hs1   = (float*)(smem + LDS_HS1);    // [16][64]
    unsigned short* lists = (unsigned short*)(smem + LDS_LISTS);
    int*            lcnt  = (int*)(smem + LDS_LCNT);

    const int tid  = threadIdx.x;
    const int wv   = tid >> 6, lane = tid & 63;
    const int c0   = blockIdx.x * COLS;

    // ---------------- P0: prologue ----------------
    for (int i = tid; i < FEAT * H1DIM; i += NTHR) {     // coalesced W1 read
        float v = W1[i];
        int j = i / FEAT, k = i - j * FEAT;              // W1[j][k]
        w1p[(k >> 2) * (H1DIM * 4) + j * 4 + (k & 3)] = v;
    }
    for (int i = tid; i < H1DIM * H2DIM; i += NTHR) {    // coalesced W2 read
        float v = W2[i];                                  // W2[j2][k]
        w2t[(i & 63) * H2DIM + (i >> 6)] = v;
    }
    if (tid < COLS) lcnt[tid] = 0;
    __syncthreads();

    // ---------------- P1: panel scan ----------------
    {
        const fvec4* H4 = reinterpret_cast<const fvec4*>(H);
        const int rq = tid >> 2;          // row offset within step (0..127)
        const int q  = tid & 3;           // float4 group -> cols q*4..q*4+3
        const int cb4 = (c0 >> 2) + q;
        #define APPEND(vv, rowi)                                             \
            if (vv.x != 0.f || vv.y != 0.f || vv.z != 0.f || vv.w != 0.f) {  \
                float vals[4] = {vv.x, vv.y, vv.z, vv.w};                    \
                _Pragma("unroll")                                            \
                for (int c = 0; c < 4; ++c) {                                \
                    if (vals[c] != 0.0f) {                                   \
                        int lc = q * 4 + c;                                  \
                        int p = atomicAdd(&lcnt[lc], 1);                     \
                        if (p < MAXK)                                        \
                            lists[lc * MAXK + p] = (unsigned short)(rowi);   \
                    }                                                        \
                }                                                            \
            }
        for (int o = 0; o < NN / 128; o += 4) {           // 4 loads in flight
            int r0 = (o + 0) * 128 + rq;
            int r1 = (o + 1) * 128 + rq;
            int r2 = (o + 2) * 128 + rq;
            int r3 = (o + 3) * 128 + rq;
            fvec4 a0 = H4[(size_t)r0 * (MM / 4) + cb4];
            fvec4 a1 = H4[(size_t)r1 * (MM / 4) + cb4];
            fvec4 a2 = H4[(size_t)r2 * (MM / 4) + cb4];
            fvec4 a3 = H4[(size_t)r3 * (MM / 4) + cb4];
            APPEND(a0, r0) APPEND(a1, r1) APPEND(a2, r2) APPEND(a3, r3)
        }
        #undef APPEND
    }
    __syncthreads();

    // ---------------- P2: stats (wave w -> edges 2w, 2w+1) ----------------
    {
        const float tval = tptr[0];
        #pragma unroll
        for (int e = 0; e < 2; ++e) {
            const int lc = wv * 2 + e;
            int K = lcnt[lc]; if (K > MAXK) K = MAXK;
            const unsigned short* lst = lists + lc * MAXK;
            float sx = 0.f, sy = 0.f, s2x = 0.f, s2y = 0.f;
            float mxx = -BIGF, mxy = -BIGF, mnx = BIGF, mny = BIGF;
            const float* xb = x + 2 * lane;
            int i = 0;
            for (; i + 4 <= K; i += 4) {
                ushort4 nv = *reinterpret_cast<const ushort4*>(lst + i);
                float2 v0 = *reinterpret_cast<const float2*>(xb + (int)nv.x * DD);
                float2 v1 = *reinterpret_cast<const float2*>(xb + (int)nv.y * DD);
                float2 v2 = *reinterpret_cast<const float2*>(xb + (int)nv.z * DD);
                float2 v3 = *reinterpret_cast<const float2*>(xb + (int)nv.w * DD);
                sx  += (v0.x + v1.x) + (v2.x + v3.x);
                sy  += (v0.y + v1.y) + (v2.y + v3.y);
                s2x += (v0.x*v0.x + v1.x*v1.x) + (v2.x*v2.x + v3.x*v3.x);
                s2y += (v0.y*v0.y + v1.y*v1.y) + (v2.y*v2.y + v3.y*v3.y);
                mxx = fmaxf(mxx, fmaxf(fmaxf(v0.x, v1.x), fmaxf(v2.x, v3.x)));
                mxy = fmaxf(mxy, fmaxf(fmaxf(v0.y, v1.y), fmaxf(v2.y, v3.y)));
                mnx = fminf(mnx, fminf(fminf(v0.x, v1.x), fminf(v2.x, v3.x)));
                mny = fminf(mny, fminf(fminf(v0.y, v1.y), fminf(v2.y, v3.y)));
            }
            for (; i < K; ++i) {
                float2 v = *reinterpret_cast<const float2*>(xb + (int)lst[i] * DD);
                sx += v.x; sy += v.y; s2x += v.x*v.x; s2y += v.y*v.y;
                mxx = fmaxf(mxx, v.x); mxy = fmaxf(mxy, v.y);
                mnx = fminf(mnx, v.x); mny = fminf(mny, v.y);
            }
            float deg = (K > 0) ? (float)K : 1.0f;
            float mux = sx / deg, muy = sy / deg;
            float sgx = sqrtf(fmaxf(s2x / deg - mux * mux, 1e-8f));
            float sgy = sqrtf(fmaxf(s2y / deg - muy * muy, 1e-8f));
            float dlx = (K > 0) ? (mxx - mnx) : 0.0f;
            float dly = (K > 0) ? (mxy - mny) : 0.0f;
            float* f = lsf + lc * FEAT;
            f[2*lane]          = mux;  f[2*lane + 1]        = muy;
            f[DD + 2*lane]     = sgx;  f[DD + 2*lane + 1]   = sgy;
            f[2*DD + 2*lane]   = dlx;  f[2*DD + 2*lane + 1] = dly;
            if (lane < TDIM)
                f[3*DD + lane] = fmaxf(tval * Wt[lane] + bt[lane], 0.0f);
        }
    }
    __syncthreads();

    // ---------------- P3: MLP (waves 0-3, 4 rows each) ----------------
    if (wv < 4) {
        const float4* W1P4 = reinterpret_cast<const float4*>(w1p);
        const float4* f0 = reinterpret_cast<const float4*>(lsf + (wv*4 + 0) * FEAT);
        const float4* f1 = reinterpret_cast<const float4*>(lsf + (wv*4 + 1) * FEAT);
        const float4* f2 = reinterpret_cast<const float4*>(lsf + (wv*4 + 2) * FEAT);
        const float4* f3 = reinterpret_cast<const float4*>(lsf + (wv*4 + 3) * FEAT);

        float bb = b1[lane];
        float acc0 = bb, acc1 = bb, acc2 = bb, acc3 = bb;
        #pragma unroll 4
        for (int g = 0; g < KGROUPS; ++g) {
            float4 w = W1P4[g * H1DIM + lane];     // LDS, contiguous 16B/lane
            float4 a0 = f0[g];
            float4 a1 = f1[g];
            float4 a2 = f2[g];
            float4 a3 = f3[g];
            acc0 += a0.x*w.x + a0.y*w.y + a0.z*w.z + a0.w*w.w;
            acc1 += a1.x*w.x + a1.y*w.y + a1.z*w.z + a1.w*w.w;
            acc2 += a2.x*w.x + a2.y*w.y + a2.z*w.z + a2.w*w.w;
            acc3 += a3.x*w.x + a3.y*w.y + a3.z*w.z + a3.w*w.w;
        }
        hs1[(wv*4 + 0) * H1DIM + lane] = fmaxf(acc0, 0.f);
        hs1[(wv*4 + 1) * H1DIM + lane] = fmaxf(acc1, 0.f);
        hs1[(wv*4 + 2) * H1DIM + lane] = fmaxf(acc2, 0.f);
        hs1[(wv*4 + 3) * H1DIM + lane] = fmaxf(acc3, 0.f);

        const int j2 = lane & 31;
        const int kh = (lane >> 5) * 32;
        float w3v = W3[j2];
        float b2v = b2[j2];
        #pragma unroll
        for (int r = 0; r < 4; ++r) {
            const float* h1 = hs1 + (wv*4 + r) * H1DIM;
            float a2 = 0.f;
            #pragma unroll
            for (int kk = 0; kk < 32; ++kk) {
                int k = kh + kk;
                a2 += h1[k] * w2t[k * H2DIM + j2];
            }
            a2 += __shfl_xor(a2, 32);
            float h2 = fmaxf(a2 + b2v, 0.f);
            float p = h2 * w3v;
            p += __shfl_xor(p, 16);
            p += __shfl_xor(p, 8);
            p += __shfl_xor(p, 4);
            p += __shfl_xor(p, 2);
            p += __shfl_xor(p, 1);
            if (lane == 0) out[c0 + wv*4 + r] = 1.f / (1.f + expf(-(p + b3[0])));
        }
    }
}

extern "C" void kernel_launch(void* const* d_in, const int* in_sizes, int n_in,
                              void* d_out, int out_size, void* d_ws, size_t ws_size,
                              hipStream_t stream) {
    const float* x   = (const float*)d_in[0];   // (N, D)
    const float* H   = (const float*)d_in[1];   // (N, M)
    const float* t   = (const float*)d_in[2];   // (1,)
    const float* Wt  = (const float*)d_in[3];   // (TDIM, 1)
    const float* bt  = (const float*)d_in[4];   // (TDIM,)
    const float* W1  = (const float*)d_in[5];   // (64, 416)
    const float* b1  = (const float*)d_in[6];
    const float* W2  = (const float*)d_in[7];   // (32, 64)
    const float* b2  = (const float*)d_in[8];
    const float* W3  = (const float*)d_in[9];   // (1, 32)
    const float* b3  = (const float*)d_in[10];
    float* out = (float*)d_out;

    // Opt in to >64KB dynamic LDS (gfx950 allows 160 KB/workgroup).
    // Host-side attribute set: capture-safe, idempotent.
    static int lds_attr_set = 0;   // host-side only; does not affect GPU work
    hipFuncSetAttribute((const void*)hyperedge_fused,
                        hipFuncAttributeMaxDynamicSharedMemorySize, LDS_TOTAL);

    hyperedge_fused<<<NBLK, NTHR, LDS_TOTAL, stream>>>(
        x, H, t, Wt, bt, W1, b1, W2, b2, W3, b3, out);
}

// Round 9
// 63.831 us; speedup vs baseline: 5.7267x; 1.0950x over previous
//
#include <hip/hip_runtime.h>
#include <math.h>

#define NN 8192
#define MM 4096
#define DD 128
#define TDIM 32
#define H1DIM 64
#define H2DIM 32
#define FEAT (3*DD + TDIM)   // 416
#define KGROUPS (FEAT/4)     // 104
#define MAXK 256
#define BIGF 1e30f
#define COLS 16              // hyperedges per block
#define NBLK (MM/COLS)       // 256 blocks
#define NTHR 1024            // 16 waves

// LDS layout (bytes):
#define LDS_W1P   0          //  26624 f = 106496  w1p[(g*64+j)*4+c] = W1[j][4g+c]
#define LDS_W2T   106496     //   2048 f =   8192  w2t[k*32+j2] = W2[j2][k]
#define LDS_LSF   114688     // 16*416 f =  26624  feature rows
#define LDS_HS1   141312     //  16*64 f =   4096  layer-1 activations
#define LDS_LISTS 145408     // 16*256 u16 = 8192  member node ids per edge
#define LDS_LCNT  153600     //     16 i =     64  member counts
#define LDS_TOTAL 153664

typedef float fvec4 __attribute__((ext_vector_type(4)));

// ONE kernel node. Block b owns hyperedges [16b, 16b+16).
//   P0 prologue: W1->LDS packed, W2T->LDS, lcnt=0
//   P1 scan:     8192x16 column panel of H; 8-deep load batches (all loads
//                issued before any APPEND -> 8 in flight/lane), DS-atomic
//                append of nonzero row ids to LDS lists
//   P2 stats:    wave w -> edge w: mean/sigma/range via coalesced float2
//                gathers of x rows -> feature row in LDS
//   P3 mlp:      wave w -> row w: 416->64->32->1 sigmoid from LDS
__global__ __launch_bounds__(NTHR, 1) void hyperedge_fused(
        const float* __restrict__ x,   const float* __restrict__ H,
        const float* __restrict__ tptr,const float* __restrict__ Wt,
        const float* __restrict__ bt,
        const float* __restrict__ W1,  const float* __restrict__ b1,
        const float* __restrict__ W2,  const float* __restrict__ b2,
        const float* __restrict__ W3,  const float* __restrict__ b3,
        float* __restrict__ out) {
    extern __shared__ char smem[];
    float*          w1p   = (float*)(smem + LDS_W1P);
    float*          w2t   = (float*)(smem + LDS_W2T);
    float*          lsf   = (float*)(smem + LDS_LSF);    // [16][416]
    float*          hs1   = (float*)(smem + LDS_HS1);    // [16][64]
    unsigned short* lists = (unsigned short*)(smem + LDS_LISTS);
    int*            lcnt  = (int*)(smem + LDS_LCNT);

    const int tid  = threadIdx.x;
    const int wv   = tid >> 6, lane = tid & 63;
    const int c0   = blockIdx.x * COLS;

    // ---------------- P0: prologue ----------------
    for (int i = tid; i < FEAT * H1DIM; i += NTHR) {     // coalesced W1 read
        float v = W1[i];
        int j = i / FEAT, k = i - j * FEAT;              // W1[j][k]
        w1p[(k >> 2) * (H1DIM * 4) + j * 4 + (k & 3)] = v;
    }
    for (int i = tid; i < H1DIM * H2DIM; i += NTHR) {    // coalesced W2 read
        w2t[(i & 63) * H2DIM + (i >> 6)] = W2[i];        // W2[j2][k]
    }
    if (tid < COLS) lcnt[tid] = 0;
    __syncthreads();

    // ---------------- P1: panel scan (8-deep load batches) ----------------
    {
        const fvec4* H4 = reinterpret_cast<const fvec4*>(H);
        const int rq = tid >> 2;              // row offset (0..255)
        const int q  = tid & 3;               // float4 group -> cols q*4..q*4+3
        const size_t cb4 = (size_t)(c0 >> 2) + q;
        #define APPEND(vv, rowi)                                             \
            if (vv.x != 0.f || vv.y != 0.f || vv.z != 0.f || vv.w != 0.f) {  \
                float vals[4] = {vv.x, vv.y, vv.z, vv.w};                    \
                _Pragma("unroll")                                            \
                for (int c = 0; c < 4; ++c) {                                \
                    if (vals[c] != 0.0f) {                                   \
                        int lc = q * 4 + c;                                  \
                        int p = atomicAdd(&lcnt[lc], 1);                     \
                        if (p < MAXK)                                        \
                            lists[lc * MAXK + p] = (unsigned short)(rowi);   \
                    }                                                        \
                }                                                            \
            }
        // 32 rows/thread in 4 batches of 8; all 8 loads issued before use.
        for (int s = 0; s < NN / 256; s += 8) {
            fvec4 a[8];
            int   r[8];
            #pragma unroll
            for (int u = 0; u < 8; ++u) {
                r[u] = (s + u) * 256 + rq;
                a[u] = H4[(size_t)r[u] * (MM / 4) + cb4];
            }
            #pragma unroll
            for (int u = 0; u < 8; ++u) { APPEND(a[u], r[u]) }
        }
        #undef APPEND
    }
    __syncthreads();

    // ---------------- P2: stats (wave w -> edge w) ----------------
    {
        const float tval = tptr[0];
        const int lc = wv;
        int K = lcnt[lc]; if (K > MAXK) K = MAXK;
        const unsigned short* lst = lists + lc * MAXK;
        float sx = 0.f, sy = 0.f, s2x = 0.f, s2y = 0.f;
        float mxx = -BIGF, mxy = -BIGF, mnx = BIGF, mny = BIGF;
        const float* xb = x + 2 * lane;
        int i = 0;
        for (; i + 4 <= K; i += 4) {
            ushort4 nv = *reinterpret_cast<const ushort4*>(lst + i);
            float2 v0 = *reinterpret_cast<const float2*>(xb + (int)nv.x * DD);
            float2 v1 = *reinterpret_cast<const float2*>(xb + (int)nv.y * DD);
            float2 v2 = *reinterpret_cast<const float2*>(xb + (int)nv.z * DD);
            float2 v3 = *reinterpret_cast<const float2*>(xb + (int)nv.w * DD);
            sx  += (v0.x + v1.x) + (v2.x + v3.x);
            sy  += (v0.y + v1.y) + (v2.y + v3.y);
            s2x += (v0.x*v0.x + v1.x*v1.x) + (v2.x*v2.x + v3.x*v3.x);
            s2y += (v0.y*v0.y + v1.y*v1.y) + (v2.y*v2.y + v3.y*v3.y);
            mxx = fmaxf(mxx, fmaxf(fmaxf(v0.x, v1.x), fmaxf(v2.x, v3.x)));
            mxy = fmaxf(mxy, fmaxf(fmaxf(v0.y, v1.y), fmaxf(v2.y, v3.y)));
            mnx = fminf(mnx, fminf(fminf(v0.x, v1.x), fminf(v2.x, v3.x)));
            mny = fminf(mny, fminf(fminf(v0.y, v1.y), fminf(v2.y, v3.y)));
        }
        for (; i < K; ++i) {
            float2 v = *reinterpret_cast<const float2*>(xb + (int)lst[i] * DD);
            sx += v.x; sy += v.y; s2x += v.x*v.x; s2y += v.y*v.y;
            mxx = fmaxf(mxx, v.x); mxy = fmaxf(mxy, v.y);
            mnx = fminf(mnx, v.x); mny = fminf(mny, v.y);
        }
        float deg = (K > 0) ? (float)K : 1.0f;
        float mux = sx / deg, muy = sy / deg;
        float sgx = sqrtf(fmaxf(s2x / deg - mux * mux, 1e-8f));
        float sgy = sqrtf(fmaxf(s2y / deg - muy * muy, 1e-8f));
        float dlx = (K > 0) ? (mxx - mnx) : 0.0f;
        float dly = (K > 0) ? (mxy - mny) : 0.0f;
        float* f = lsf + lc * FEAT;
        f[2*lane]          = mux;  f[2*lane + 1]        = muy;
        f[DD + 2*lane]     = sgx;  f[DD + 2*lane + 1]   = sgy;
        f[2*DD + 2*lane]   = dlx;  f[2*DD + 2*lane + 1] = dly;
        if (lane < TDIM)
            f[3*DD + lane] = fmaxf(tval * Wt[lane] + bt[lane], 0.0f);
    }
    __syncthreads();

    // ---------------- P3: MLP (wave w -> row w) ----------------
    {
        const float4* W1P4 = reinterpret_cast<const float4*>(w1p);
        const float4* fr   = reinterpret_cast<const float4*>(lsf + wv * FEAT);
        float acc = b1[lane];
        #pragma unroll 8
        for (int g = 0; g < KGROUPS; ++g) {
            float4 w = W1P4[g * H1DIM + lane];   // LDS, 16B/lane contiguous
            float4 a = fr[g];                     // LDS broadcast
            acc += a.x*w.x + a.y*w.y + a.z*w.z + a.w*w.w;
        }
        hs1[wv * H1DIM + lane] = fmaxf(acc, 0.f);
        // same-wave write->read of hs1 row: lockstep wave, no barrier needed
        const int j2 = lane & 31;
        const int kh = (lane >> 5) * 32;
        float a2 = 0.f;
        #pragma unroll
        for (int kk = 0; kk < 32; ++kk) {
            int k = kh + kk;
            a2 += hs1[wv * H1DIM + k] * w2t[k * H2DIM + j2];
        }
        a2 += __shfl_xor(a2, 32);
        float h2 = fmaxf(a2 + b2[j2], 0.f);
        float p = h2 * W3[j2];
        p += __shfl_xor(p, 16);
        p += __shfl_xor(p, 8);
        p += __shfl_xor(p, 4);
        p += __shfl_xor(p, 2);
        p += __shfl_xor(p, 1);
        if (lane == 0) out[c0 + wv] = 1.f / (1.f + expf(-(p + b3[0])));
    }
}

extern "C" void kernel_launch(void* const* d_in, const int* in_sizes, int n_in,
                              void* d_out, int out_size, void* d_ws, size_t ws_size,
                              hipStream_t stream) {
    const float* x   = (const float*)d_in[0];   // (N, D)
    const float* H   = (const float*)d_in[1];   // (N, M)
    const float* t   = (const float*)d_in[2];   // (1,)
    const float* Wt  = (const float*)d_in[3];   // (TDIM, 1)
    const float* bt  = (const float*)d_in[4];   // (TDIM,)
    const float* W1  = (const float*)d_in[5];   // (64, 416)
    const float* b1  = (const float*)d_in[6];
    const float* W2  = (const float*)d_in[7];   // (32, 64)
    const float* b2  = (const float*)d_in[8];
    const float* W3  = (const float*)d_in[9];   // (1, 32)
    const float* b3  = (const float*)d_in[10];
    float* out = (float*)d_out;

    hipFuncSetAttribute((const void*)hyperedge_fused,
                        hipFuncAttributeMaxDynamicSharedMemorySize, LDS_TOTAL);

    hyperedge_fused<<<NBLK, NTHR, LDS_TOTAL, stream>>>(
        x, H, t, Wt, bt, W1, b1, W2, b2, W3, b3, out);
}

// Round 10
// 53.758 us; speedup vs baseline: 6.7998x; 1.1874x over previous
//
#include <hip/hip_runtime.h>
#include <math.h>

#define NN 8192
#define MM 4096
#define DD 128
#define TDIM 32
#define H1DIM 64
#define H2DIM 32
#define FEAT (3*DD + TDIM)   // 416
#define KGROUPS (FEAT/4)     // 104
#define BIGF 1e30f

#define NCHUNK 512           // scan blocks; each owns 16 rows of H
#define CAP 8                // max members per (chunk, edge); P(overflow)~1e-13
#define LISTCAP 256          // max members per edge in stats kernel

// ---- stats/MLP kernel LDS layout (bytes) ----
#define LDS_W1P   0          //  26624 f = 106496  w1p[(g*64+j)*4+c] = W1[j][4g+c]
#define LDS_W2T   106496     //   2048 f =   8192  w2t[k*32+j2] = W2[j2][k]
#define LDS_LSF   114688     // 16*416 f =  26624  feature rows
#define LDS_HS1   141312     //  16*64 f =   4096  layer-1 activations
#define LDS_LISTS 145408     // 16*256 u16 = 8192  member node ids per edge
#define LDS_LCNT  153600     //     16 i =     64  member counts
#define LDS_TOTAL 153664

typedef float fvec4 __attribute__((ext_vector_type(4)));

// Node 1: chunked CSC scan. Block c reads rows [16c,16c+16) of H — 256 KB
// CONTIGUOUS (full-stream, DRAM-page-perfect), 8 loads in flight per lane.
// Nonzeros appended to the block's PRIVATE global segment idxg[c][m][slot]
// via block-local LDS counters (zeroed here -> no memset node, no global
// atomics). Counts written coalesced as packed u32.
__global__ __launch_bounds__(256) void scan_csc(
        const float* __restrict__ H,
        unsigned short* __restrict__ idxg, unsigned char* __restrict__ cntg) {
    __shared__ int lcnt[MM];                 // 16 KB
    const int tid = threadIdx.x;
    const int c   = blockIdx.x;
    for (int i = tid; i < MM; i += 256) lcnt[i] = 0;
    __syncthreads();

    const fvec4* H4 = reinterpret_cast<const fvec4*>(H) + (size_t)c * (16 * MM / 4);
    const int r0 = c * 16;
    unsigned short* seg = idxg + (size_t)c * MM * CAP;

    for (int s = 0; s < 8; ++s) {            // 64 float4/thread in 8-deep batches
        fvec4 a[8]; int o[8];
        #pragma unroll
        for (int u = 0; u < 8; ++u) {
            o[u] = s * 2048 + u * 256 + tid;
            a[u] = H4[o[u]];
        }
        #pragma unroll
        for (int u = 0; u < 8; ++u) {
            fvec4 v = a[u];
            if (v.x != 0.f || v.y != 0.f || v.z != 0.f || v.w != 0.f) {
                int r  = r0 + (o[u] >> 10);          // 1024 float4s per row
                int mb = (o[u] & 1023) * 4;
                float vals[4] = {v.x, v.y, v.z, v.w};
                #pragma unroll
                for (int q = 0; q < 4; ++q) {
                    if (vals[q] != 0.0f) {
                        int m = mb + q;
                        int p = atomicAdd(&lcnt[m], 1);
                        if (p < CAP) seg[m * CAP + p] = (unsigned short)r;
                    }
                }
            }
        }
    }
    __syncthreads();

    unsigned int* dst = (unsigned int*)(cntg + (size_t)c * MM);
    for (int i = tid; i < MM / 4; i += 256) {   // coalesced packed counts
        unsigned int k0 = min(lcnt[4*i + 0], CAP);
        unsigned int k1 = min(lcnt[4*i + 1], CAP);
        unsigned int k2 = min(lcnt[4*i + 2], CAP);
        unsigned int k3 = min(lcnt[4*i + 3], CAP);
        dst[i] = k0 | (k1 << 8) | (k2 << 16) | (k3 << 24);
    }
}

// Node 2: list-merge + stats + MLP. 256 blocks x 1024 thr; block owns edges
// [16b,16b+16), wave w owns edge w.
//   B0: pack W1/W2 into LDS, zero list counters
//   B1: 8192 (chunk,edge) pairs / 1024 thr: u64 count-load, append ids from
//       idxg segments into LDS lists (DS atomics; fully parallel)
//   B2: per-wave stats (proven float2-gather)    B3: per-wave MLP
__global__ __launch_bounds__(1024, 1) void stats_mlp(
        const float* __restrict__ x,
        const unsigned short* __restrict__ idxg, const unsigned char* __restrict__ cntg,
        const float* __restrict__ tptr, const float* __restrict__ Wt,
        const float* __restrict__ bt,
        const float* __restrict__ W1, const float* __restrict__ b1,
        const float* __restrict__ W2, const float* __restrict__ b2,
        const float* __restrict__ W3, const float* __restrict__ b3,
        float* __restrict__ out) {
    extern __shared__ char smem[];
    float*          w1p   = (float*)(smem + LDS_W1P);
    float*          w2t   = (float*)(smem + LDS_W2T);
    float*          lsf   = (float*)(smem + LDS_LSF);     // [16][416]
    float*          hs1   = (float*)(smem + LDS_HS1);     // [16][64]
    unsigned short* lists = (unsigned short*)(smem + LDS_LISTS);
    int*            lcnt2 = (int*)(smem + LDS_LCNT);

    const int tid = threadIdx.x;
    const int wv  = tid >> 6, lane = tid & 63;
    const int m0  = blockIdx.x * 16;

    // ---- B0: prologue ----
    for (int i = tid; i < FEAT * H1DIM; i += 1024) {      // coalesced W1 read
        float v = W1[i];
        int j = i / FEAT, k = i - j * FEAT;               // W1[j][k]
        w1p[(k >> 2) * (H1DIM * 4) + j * 4 + (k & 3)] = v;
    }
    for (int i = tid; i < H1DIM * H2DIM; i += 1024) {     // coalesced W2 read
        w2t[(i & 63) * H2DIM + (i >> 6)] = W2[i];         // W2[j2][k]
    }
    if (tid < 16) lcnt2[tid] = 0;
    __syncthreads();

    // ---- B1: merge chunk segments into per-edge LDS lists ----
    {
        int i  = tid * 8;              // (c,e) pair base: c = i>>4, e0 = i&15
        int c  = i >> 4, e0 = i & 15;
        const unsigned char* cp = cntg + (size_t)c * MM + m0 + e0;
        unsigned long long k8 = *reinterpret_cast<const unsigned long long*>(cp);
        #pragma unroll
        for (int j = 0; j < 8; ++j) {
            int k = (int)((k8 >> (8 * j)) & 0xFF);
            if (k) {
                int e = e0 + j, m = m0 + e;
                int base = atomicAdd(&lcnt2[e], k);
                const unsigned short* src = idxg + ((size_t)c * MM + m) * CAP;
                for (int q = 0; q < k; ++q) {
                    int p = base + q;
                    if (p < LISTCAP) lists[e * LISTCAP + p] = src[q];
                }
            }
        }
    }
    __syncthreads();

    // ---- B2: stats (wave wv -> edge wv) ----
    {
        const float tval = tptr[0];
        int K = lcnt2[wv]; if (K > LISTCAP) K = LISTCAP;
        const unsigned short* lst = lists + wv * LISTCAP;
        float sx = 0.f, sy = 0.f, s2x = 0.f, s2y = 0.f;
        float mxx = -BIGF, mxy = -BIGF, mnx = BIGF, mny = BIGF;
        const float* xb = x + 2 * lane;
        int i = 0;
        for (; i + 4 <= K; i += 4) {
            ushort4 nv = *reinterpret_cast<const ushort4*>(lst + i);
            float2 v0 = *reinterpret_cast<const float2*>(xb + (int)nv.x * DD);
            float2 v1 = *reinterpret_cast<const float2*>(xb + (int)nv.y * DD);
            float2 v2 = *reinterpret_cast<const float2*>(xb + (int)nv.z * DD);
            float2 v3 = *reinterpret_cast<const float2*>(xb + (int)nv.w * DD);
            sx  += (v0.x + v1.x) + (v2.x + v3.x);
            sy  += (v0.y + v1.y) + (v2.y + v3.y);
            s2x += (v0.x*v0.x + v1.x*v1.x) + (v2.x*v2.x + v3.x*v3.x);
            s2y += (v0.y*v0.y + v1.y*v1.y) + (v2.y*v2.y + v3.y*v3.y);
            mxx = fmaxf(mxx, fmaxf(fmaxf(v0.x, v1.x), fmaxf(v2.x, v3.x)));
            mxy = fmaxf(mxy, fmaxf(fmaxf(v0.y, v1.y), fmaxf(v2.y, v3.y)));
            mnx = fminf(mnx, fminf(fminf(v0.x, v1.x), fminf(v2.x, v3.x)));
            mny = fminf(mny, fminf(fminf(v0.y, v1.y), fminf(v2.y, v3.y)));
        }
        for (; i < K; ++i) {
            float2 v = *reinterpret_cast<const float2*>(xb + (int)lst[i] * DD);
            sx += v.x; sy += v.y; s2x += v.x*v.x; s2y += v.y*v.y;
            mxx = fmaxf(mxx, v.x); mxy = fmaxf(mxy, v.y);
            mnx = fminf(mnx, v.x); mny = fminf(mny, v.y);
        }
        float deg = (K > 0) ? (float)K : 1.0f;
        float mux = sx / deg, muy = sy / deg;
        float sgx = sqrtf(fmaxf(s2x / deg - mux * mux, 1e-8f));
        float sgy = sqrtf(fmaxf(s2y / deg - muy * muy, 1e-8f));
        float dlx = (K > 0) ? (mxx - mnx) : 0.0f;
        float dly = (K > 0) ? (mxy - mny) : 0.0f;
        float* f = lsf + wv * FEAT;
        f[2*lane]          = mux;  f[2*lane + 1]        = muy;
        f[DD + 2*lane]     = sgx;  f[DD + 2*lane + 1]   = sgy;
        f[2*DD + 2*lane]   = dlx;  f[2*DD + 2*lane + 1] = dly;
        if (lane < TDIM)
            f[3*DD + lane] = fmaxf(tval * Wt[lane] + bt[lane], 0.0f);
    }
    __syncthreads();

    // ---- B3: MLP (wave wv -> row wv) ----
    {
        const float4* W1P4 = reinterpret_cast<const float4*>(w1p);
        const float4* fr   = reinterpret_cast<const float4*>(lsf + wv * FEAT);
        float acc = b1[lane];
        #pragma unroll 8
        for (int g = 0; g < KGROUPS; ++g) {
            float4 w = W1P4[g * H1DIM + lane];   // LDS, 16B/lane contiguous
            float4 a = fr[g];                     // LDS broadcast
            acc += a.x*w.x + a.y*w.y + a.z*w.z + a.w*w.w;
        }
        hs1[wv * H1DIM + lane] = fmaxf(acc, 0.f);
        // same-wave write->read of hs1 row: lockstep wave, no barrier needed
        const int j2 = lane & 31;
        const int kh = (lane >> 5) * 32;
        float a2 = 0.f;
        #pragma unroll
        for (int kk = 0; kk < 32; ++kk) {
            int k = kh + kk;
            a2 += hs1[wv * H1DIM + k] * w2t[k * H2DIM + j2];
        }
        a2 += __shfl_xor(a2, 32);
        float h2 = fmaxf(a2 + b2[j2], 0.f);
        float p = h2 * W3[j2];
        p += __shfl_xor(p, 16);
        p += __shfl_xor(p, 8);
        p += __shfl_xor(p, 4);
        p += __shfl_xor(p, 2);
        p += __shfl_xor(p, 1);
        if (lane == 0) out[m0 + wv] = 1.f / (1.f + expf(-(p + b3[0])));
    }
}

extern "C" void kernel_launch(void* const* d_in, const int* in_sizes, int n_in,
                              void* d_out, int out_size, void* d_ws, size_t ws_size,
                              hipStream_t stream) {
    const float* x   = (const float*)d_in[0];   // (N, D)
    const float* H   = (const float*)d_in[1];   // (N, M)
    const float* t   = (const float*)d_in[2];   // (1,)
    const float* Wt  = (const float*)d_in[3];   // (TDIM, 1)
    const float* bt  = (const float*)d_in[4];   // (TDIM,)
    const float* W1  = (const float*)d_in[5];   // (64, 416)
    const float* b1  = (const float*)d_in[6];
    const float* W2  = (const float*)d_in[7];   // (32, 64)
    const float* b2  = (const float*)d_in[8];
    const float* W3  = (const float*)d_in[9];   // (1, 32)
    const float* b3  = (const float*)d_in[10];
    float* out = (float*)d_out;

    // workspace: idxg 512*4096*8 u16 = 32 MB; cntg 512*4096 u8 = 2 MB
    unsigned short* idxg = (unsigned short*)d_ws;
    unsigned char*  cntg = (unsigned char*)(idxg + (size_t)NCHUNK * MM * CAP);

    hipFuncSetAttribute((const void*)stats_mlp,
                        hipFuncAttributeMaxDynamicSharedMemorySize, LDS_TOTAL);

    scan_csc<<<NCHUNK, 256, 0, stream>>>(H, idxg, cntg);
    stats_mlp<<<MM / 16, 1024, LDS_TOTAL, stream>>>(
        x, idxg, cntg, t, Wt, bt, W1, b1, W2, b2, W3, b3, out);
}